// Round 10
// baseline (258.690 us; speedup 1.0000x reference)
//
#include <hip/hip_runtime.h>
#include <hip/hip_bf16.h>

// L=256, B=32, H=8, d_head=64, m=256, feature dim 2m=512, D_MODEL=512
#define L_SEQ 256
#define B_SZ  32
#define NH    8
#define DH    64
#define DM    512
#define FD    512
#define PM    256
#define ROWS  8192
#define QKVN  2048

typedef __bf16 bf16x8 __attribute__((ext_vector_type(8)));
typedef float f32x4 __attribute__((ext_vector_type(4)));
#define MFMA16(a, b, c) __builtin_amdgcn_mfma_f32_16x16x32_bf16((a), (b), (c), 0, 0, 0)

static __device__ __forceinline__ void stmix(void* p, long i, float v, int f32) {
  if (f32) ((float*)p)[i] = v;
  else     ((__bf16*)p)[i] = (__bf16)v;
}

// ---------------------------------------------------------------------------
// P0: prep — probe + h-cvt + 3 transposes + tiny cvts in one launch
// (validated rounds 7-9). Every block re-derives the dtype flag inline.
// ---------------------------------------------------------------------------
#define PREP_HB   2048
#define PREP_WT   256
#define PREP_WOT  64
#define PREP_PJ   4
#define PREP_TINY 1
#define PREP_BLOCKS (PREP_HB + PREP_WT + PREP_WOT + PREP_PJ + PREP_TINY)

__global__ __launch_bounds__(256) void prep(
    const void* __restrict__ h, const void* __restrict__ wqkv,
    const void* __restrict__ wo, const void* __restrict__ proj,
    const void* __restrict__ pi0, const void* __restrict__ pi1,
    const void* __restrict__ gam, const void* __restrict__ bet,
    int* __restrict__ flag, __bf16* __restrict__ hb, __bf16* __restrict__ wt,
    __bf16* __restrict__ wot, __bf16* __restrict__ projT,
    __bf16* __restrict__ pi0b, __bf16* __restrict__ pi1b,
    __bf16* __restrict__ gamb, __bf16* __restrict__ betb) {
  __shared__ float T[64][69];
  __shared__ int red[256];
  const int tid = threadIdx.x;
  int cnt = 0;
  {
    const unsigned short* hbits = (const unsigned short*)h;
    for (int i = 0; i < 16; ++i) {
      const unsigned short u = hbits[tid * 16 + i];
      if (((u >> 7) & 0xFF) >= 0xA0) ++cnt;
    }
  }
  red[tid] = cnt; __syncthreads();
  for (int s = 128; s > 0; s >>= 1) { if (tid < s) red[tid] += red[tid + s]; __syncthreads(); }
  const int f32 = (red[0] >= 64) ? 1 : 0;
  __syncthreads();

  const int blk = blockIdx.x;
  if (blk < PREP_HB) {
    const int i = blk * 256 + tid;
    if (f32) {
      const f32x4* s = (const f32x4*)h;
      const f32x4 a = s[i * 2], b = s[i * 2 + 1];
      bf16x8 t;
      t[0] = (__bf16)a[0]; t[1] = (__bf16)a[1]; t[2] = (__bf16)a[2]; t[3] = (__bf16)a[3];
      t[4] = (__bf16)b[0]; t[5] = (__bf16)b[1]; t[6] = (__bf16)b[2]; t[7] = (__bf16)b[3];
      *reinterpret_cast<bf16x8*>(hb + (long)i * 8) = t;
    } else {
      *reinterpret_cast<bf16x8*>(hb + (long)i * 8) = ((const bf16x8*)h)[i];
    }
    return;
  }
  const void* src; __bf16* dst; int M, N, n0, m0;
  if (blk < PREP_HB + PREP_WT) {
    const int x = blk - PREP_HB;
    src = wqkv; dst = wt; M = 512; N = 2048; n0 = (x & 31) * 64; m0 = (x >> 5) * 64;
  } else if (blk < PREP_HB + PREP_WT + PREP_WOT) {
    const int x = blk - PREP_HB - PREP_WT;
    src = wo; dst = wot; M = 512; N = 512; n0 = (x & 7) * 64; m0 = (x >> 3) * 64;
  } else if (blk < PREP_HB + PREP_WT + PREP_WOT + PREP_PJ) {
    const int x = blk - PREP_HB - PREP_WT - PREP_WOT;
    src = proj; dst = projT; M = 64; N = 256; n0 = x * 64; m0 = 0;
  } else {
    if (tid == 0) flag[0] = f32;
    if (f32) {
      const float* s0 = (const float*)pi0; const float* s1 = (const float*)pi1;
      const float* s2 = (const float*)gam; const float* s3 = (const float*)bet;
      for (int i = tid; i < NH * 256; i += 256) { pi0b[i] = (__bf16)s0[i]; pi1b[i] = (__bf16)s1[i]; }
      for (int i = tid; i < DM; i += 256)      { gamb[i] = (__bf16)s2[i]; betb[i] = (__bf16)s3[i]; }
    } else {
      const __bf16* s0 = (const __bf16*)pi0; const __bf16* s1 = (const __bf16*)pi1;
      const __bf16* s2 = (const __bf16*)gam; const __bf16* s3 = (const __bf16*)bet;
      for (int i = tid; i < NH * 256; i += 256) { pi0b[i] = s0[i]; pi1b[i] = s1[i]; }
      for (int i = tid; i < DM; i += 256)      { gamb[i] = s2[i]; betb[i] = s3[i]; }
    }
    return;
  }
  if (f32) {
    const float* s = (const float*)src;
#pragma unroll
    for (int rep = 0; rep < 16; ++rep) {
      const int i = rep * 4 + (tid >> 6), j = tid & 63;
      T[i][j] = s[(long)(m0 + i) * N + n0 + j];
    }
  } else {
    const __bf16* s = (const __bf16*)src;
#pragma unroll
    for (int rep = 0; rep < 16; ++rep) {
      const int i = rep * 4 + (tid >> 6), j = tid & 63;
      T[i][j] = (float)s[(long)(m0 + i) * N + n0 + j];
    }
  }
  __syncthreads();
#pragma unroll
  for (int rep = 0; rep < 16; ++rep) {
    const int i = rep * 4 + (tid >> 6), j = tid & 63;
    dst[(long)(n0 + i) * M + m0 + j] = (__bf16)T[j][i];
  }
}

// ---------------------------------------------------------------------------
// K1: qkv = hb @ w_qkv, 64x128 tile (round-10: 2x MFMA per staged byte vs
// 64x64), register prefetch. LDS 52 KB -> up to 3 blocks/CU.
// ---------------------------------------------------------------------------
__global__ __launch_bounds__(256) void gemm_h_wqkv(const __bf16* __restrict__ A,
                                                   const __bf16* __restrict__ Bt,
                                                   __bf16* __restrict__ C) {
  __shared__ __bf16 At[64][136];
  __shared__ __bf16 Bts[128][136];
  const int n0 = blockIdx.x * 128, m0 = blockIdx.y * 64;
  const int tid = threadIdx.x, lane = tid & 63, wv = tid >> 6;
  const int m = lane & 15, q = lane >> 4;
  const int ra = tid >> 2, ca = (tid & 3) * 32;       // A staging: 64 rows x 4x8
  const int rb = tid >> 1, cb = (tid & 1) * 64;       // B staging: 128 rows x 8x8
  const __bf16* ap = A + (long)(m0 + ra) * DM + ca;
  const __bf16* bp = Bt + (long)(n0 + rb) * DM + cb;
  f32x4 acc[8];
#pragma unroll
  for (int i = 0; i < 8; ++i) acc[i] = f32x4{0.f, 0.f, 0.f, 0.f};

  bf16x8 ar[4], br[8];
#pragma unroll
  for (int j = 0; j < 4; ++j) ar[j] = *reinterpret_cast<const bf16x8*>(ap + j * 8);
#pragma unroll
  for (int j = 0; j < 8; ++j) br[j] = *reinterpret_cast<const bf16x8*>(bp + j * 8);
  for (int k0 = 0; k0 < DM; k0 += 128) {
    __syncthreads();
#pragma unroll
    for (int j = 0; j < 4; ++j) *reinterpret_cast<bf16x8*>(&At[ra][ca + j * 8]) = ar[j];
#pragma unroll
    for (int j = 0; j < 8; ++j) *reinterpret_cast<bf16x8*>(&Bts[rb][cb + j * 8]) = br[j];
    if (k0 + 128 < DM) {
#pragma unroll
      for (int j = 0; j < 4; ++j)
        ar[j] = *reinterpret_cast<const bf16x8*>(ap + k0 + 128 + j * 8);
#pragma unroll
      for (int j = 0; j < 8; ++j)
        br[j] = *reinterpret_cast<const bf16x8*>(bp + k0 + 128 + j * 8);
    }
    __syncthreads();
#pragma unroll
    for (int kk = 0; kk < 4; ++kk) {
      const bf16x8 af = *reinterpret_cast<const bf16x8*>(&At[wv * 16 + m][kk * 32 + q * 8]);
#pragma unroll
      for (int c = 0; c < 8; ++c) {
        const bf16x8 bf = *reinterpret_cast<const bf16x8*>(&Bts[c * 16 + m][kk * 32 + q * 8]);
        acc[c] = MFMA16(af, bf, acc[c]);
      }
    }
  }
#pragma unroll
  for (int r2 = 0; r2 < 4; ++r2)
#pragma unroll
    for (int c = 0; c < 8; ++c)
      C[(long)(m0 + wv * 16 + q * 4 + r2) * QKVN + n0 + c * 16 + m] = (__bf16)acc[c][r2];
}

// ---------------------------------------------------------------------------
// K2: kf-features + FUSED vpack (round 10). Same grid (l0, bh) — the v-slice
// is the adjacent 64 cols of the same qkv rows. T aliases As[0] after the
// feature MFMA barrier; v-loads overlap the softmax epilogue.
// MFMA + in-register softmax + permuted layout col'=m*16+c (validated r8/9).
// ---------------------------------------------------------------------------
__global__ __launch_bounds__(256) void features_mfma(const __bf16* __restrict__ qkv,
                                                     const __bf16* __restrict__ projT,
                                                     const __bf16* __restrict__ pi0,
                                                     const __bf16* __restrict__ pi1,
                                                     __bf16* __restrict__ kf,
                                                     __bf16* __restrict__ vt) {
  const int l0 = blockIdx.x * 64;
  const int bh = blockIdx.y;
  const int h = bh & 7, b = bh >> 3;
  const int tid = threadIdx.x, lane = tid & 63, wv = tid >> 6;
  const int m = lane & 15, q = lane >> 4;
  __shared__ __bf16 Bs[256][72];     // projT rows (n=proj col, k=d)
  __shared__ __bf16 As[2][64][72];   // k1 / k2 tiles; As[0] re-used as vpack T
  __bf16 (*T)[72] = As[0];

  {
    const __bf16* p = projT + (long)tid * 64;
#pragma unroll
    for (int j = 0; j < 8; ++j)
      *reinterpret_cast<bf16x8*>(&Bs[tid][j * 8]) = *reinterpret_cast<const bf16x8*>(p + j * 8);
  }
  {
    const int r = tid >> 2, c0 = (tid & 3) * 16;
    const __bf16* ap = qkv + (long)((l0 + r) * B_SZ + b) * QKVN + h * 256 + 64 + c0;
#pragma unroll
    for (int t2 = 0; t2 < 2; ++t2) {
      *reinterpret_cast<bf16x8*>(&As[t2][r][c0]) =
          *reinterpret_cast<const bf16x8*>(ap + t2 * 64);
      *reinterpret_cast<bf16x8*>(&As[t2][r][c0 + 8]) =
          *reinterpret_cast<const bf16x8*>(ap + t2 * 64 + 8);
    }
  }
  float p0w[4], p1w[4];
#pragma unroll
  for (int r = 0; r < 4; ++r) {
    const int l = l0 + wv * 16 + q * 4 + r;
    p0w[r] = (float)pi0[h * 256 + l];
    p1w[r] = (float)pi1[h * 256 + l];
  }
  const float SQ = 0.35355339f;      // 64^-0.25
  const float SK2 = 0.24748737f;     // 0.7 * 64^-0.25
  __syncthreads();

  f32x4 acc1[16], acc2[16];
#pragma unroll
  for (int c = 0; c < 16; ++c) {
    acc1[c] = f32x4{0.f, 0.f, 0.f, 0.f};
    acc2[c] = f32x4{0.f, 0.f, 0.f, 0.f};
  }
#pragma unroll
  for (int kk = 0; kk < 2; ++kk) {
    const bf16x8 a1 = *reinterpret_cast<const bf16x8*>(&As[0][wv * 16 + m][kk * 32 + q * 8]);
    const bf16x8 a2 = *reinterpret_cast<const bf16x8*>(&As[1][wv * 16 + m][kk * 32 + q * 8]);
#pragma unroll
    for (int c = 0; c < 16; ++c) {
      const bf16x8 bf = *reinterpret_cast<const bf16x8*>(&Bs[c * 16 + m][kk * 32 + q * 8]);
      acc1[c] = MFMA16(a1, bf, acc1[c]);
      acc2[c] = MFMA16(a2, bf, acc2[c]);
    }
  }
  __syncthreads();                   // As reads done -> T writable
  // vpack loads (overlap with softmax below)
  {
    const int s = tid >> 2, d0 = (tid & 3) * 16;
    const __bf16* vp = qkv + ((long)((l0 + s) * B_SZ + b)) * QKVN + h * 256 + 192 + d0;
#pragma unroll
    for (int j = 0; j < 16; ++j) T[d0 + j][s] = vp[j];
  }

  float mx1[4] = {0.f, 0.f, 0.f, 0.f}, sm1[4] = {0.f, 0.f, 0.f, 0.f};
  float mx2[4] = {0.f, 0.f, 0.f, 0.f}, sm2[4] = {0.f, 0.f, 0.f, 0.f};
#pragma unroll
  for (int c = 0; c < 16; ++c)
#pragma unroll
    for (int r = 0; r < 4; ++r) {
      mx1[r] = fmaxf(mx1[r], fabsf(acc1[c][r] * SQ));
      mx2[r] = fmaxf(mx2[r], fabsf(acc2[c][r] * SK2));
    }
#pragma unroll
  for (int msk = 1; msk < 16; msk <<= 1)
#pragma unroll
    for (int r = 0; r < 4; ++r) {
      mx1[r] = fmaxf(mx1[r], __shfl_xor(mx1[r], msk));
      mx2[r] = fmaxf(mx2[r], __shfl_xor(mx2[r], msk));
    }
  float C21[4], C22[4];
#pragma unroll
  for (int r = 0; r < 4; ++r) {
    C21[r] = __expf(-2.f * mx1[r]);
    C22[r] = __expf(-2.f * mx2[r]);
  }
#pragma unroll
  for (int c = 0; c < 16; ++c)
#pragma unroll
    for (int r = 0; r < 4; ++r) {
      const float e11 = __expf(acc1[c][r] * SQ - mx1[r]);
      const float e12 = __expf(acc2[c][r] * SK2 - mx2[r]);
      sm1[r] += e11 + C21[r] * __builtin_amdgcn_rcpf(e11);
      sm2[r] += e12 + C22[r] * __builtin_amdgcn_rcpf(e12);
      acc1[c][r] = e11;
      acc2[c][r] = e12;
    }
#pragma unroll
  for (int msk = 1; msk < 16; msk <<= 1)
#pragma unroll
    for (int r = 0; r < 4; ++r) {
      sm1[r] += __shfl_xor(sm1[r], msk);
      sm2[r] += __shfl_xor(sm2[r], msk);
    }
  const long base = ((long)bh * 256 + l0 + wv * 16 + q * 4) * FD + m * 16;
#pragma unroll
  for (int r = 0; r < 4; ++r) {
    const float w1 = p0w[r] * __builtin_amdgcn_rcpf(sm1[r]);
    const float w2 = p1w[r] * __builtin_amdgcn_rcpf(sm2[r]);
    const float K1 = C21[r] * w1, K2 = C22[r] * w2;
    __bf16 pk[16], nk[16];
#pragma unroll
    for (int c = 0; c < 16; ++c) {
      const float e11 = acc1[c][r], e12 = acc2[c][r];
      pk[c] = (__bf16)(w1 * e11 + w2 * e12);
      nk[c] = (__bf16)(K1 * __builtin_amdgcn_rcpf(e11) + K2 * __builtin_amdgcn_rcpf(e12));
    }
    __bf16* op = kf + base + (long)r * FD;
    *reinterpret_cast<bf16x8*>(op)           = *reinterpret_cast<bf16x8*>(&pk[0]);
    *reinterpret_cast<bf16x8*>(op + 8)       = *reinterpret_cast<bf16x8*>(&pk[8]);
    *reinterpret_cast<bf16x8*>(op + 256)     = *reinterpret_cast<bf16x8*>(&nk[0]);
    *reinterpret_cast<bf16x8*>(op + 256 + 8) = *reinterpret_cast<bf16x8*>(&nk[8]);
  }
  // vpack store
  __syncthreads();
  {
    const int d = tid >> 2, sc = (tid & 3) * 16;
    __bf16* op = vt + ((long)bh * 64 + d) * 256 + l0 + sc;
    *reinterpret_cast<bf16x8*>(op)     = *reinterpret_cast<const bf16x8*>(&T[d][sc]);
    *reinterpret_cast<bf16x8*>(op + 8) = *reinterpret_cast<const bf16x8*>(&T[d][sc + 8]);
  }
}

// ---------------------------------------------------------------------------
// K3: flash with fused Q-features (validated round 9). Round-10: 1-D grid with
// bh = x & 255, pr = x >> 8 — the two blocks of a bh sit 256 apart (=0 mod 8)
// so round-robin dispatch lands them on the same XCD -> shared kf L2 hits.
// ---------------------------------------------------------------------------
union FlashSmem {
  struct { __bf16 Bs[256][72]; __bf16 As[64][72]; __bf16 Qtmp[64][136]; } f;
  struct { __bf16 Kc[64][136]; __bf16 Vt[80][72]; __bf16 Pt[64][72]; } mn;
};

__global__ __launch_bounds__(256, 2) void flash_mfma(const __bf16* __restrict__ qkv,
                                                     const __bf16* __restrict__ projT,
                                                     const __bf16* __restrict__ kf,
                                                     const __bf16* __restrict__ vt,
                                                     __bf16* __restrict__ att) {
  const int pr = blockIdx.x >> 8;         // 0:{0,3}  1:{1,2}
  const int bh = blockIdx.x & 255;
  const int h = bh & 7, b = bh >> 3;
  const int tid = threadIdx.x, lane = tid & 63, wv = tid >> 6;
  const int m = lane & 15, q = lane >> 4;
  const int tA = pr, tB = 3 - pr;
  __shared__ FlashSmem S;

  // ---------------- feature phase: build qA/qB ----------------
  const float SQ = 0.35355339f;          // 64^-0.25
  {
    const __bf16* p = projT + (long)tid * 64;
#pragma unroll
    for (int j = 0; j < 8; ++j)
      *reinterpret_cast<bf16x8*>(&S.f.Bs[tid][j * 8]) =
          *reinterpret_cast<const bf16x8*>(p + j * 8);
  }
  bf16x8 qA[16], qB[16];
#pragma unroll
  for (int t2 = 0; t2 < 2; ++t2) {
    const int tt = t2 ? tB : tA;
    bf16x8* qT = t2 ? qB : qA;
    {
      const int r = tid >> 2, c0 = (tid & 3) * 16;
      const __bf16* ap = qkv + (long)((tt * 64 + r) * B_SZ + b) * QKVN + h * 256 + c0;
      *reinterpret_cast<bf16x8*>(&S.f.As[r][c0])     = *reinterpret_cast<const bf16x8*>(ap);
      *reinterpret_cast<bf16x8*>(&S.f.As[r][c0 + 8]) = *reinterpret_cast<const bf16x8*>(ap + 8);
    }
    __syncthreads();
    f32x4 acc[16];
#pragma unroll
    for (int c = 0; c < 16; ++c) acc[c] = f32x4{0.f, 0.f, 0.f, 0.f};
#pragma unroll
    for (int kk = 0; kk < 2; ++kk) {
      const bf16x8 af = *reinterpret_cast<const bf16x8*>(&S.f.As[wv * 16 + m][kk * 32 + q * 8]);
#pragma unroll
      for (int c = 0; c < 16; ++c) {
        const bf16x8 bf = *reinterpret_cast<const bf16x8*>(&S.f.Bs[c * 16 + m][kk * 32 + q * 8]);
        acc[c] = MFMA16(af, bf, acc[c]);
      }
    }
    float mx[4] = {0.f, 0.f, 0.f, 0.f}, sm[4] = {0.f, 0.f, 0.f, 0.f};
#pragma unroll
    for (int c = 0; c < 16; ++c)
#pragma unroll
      for (int r = 0; r < 4; ++r) mx[r] = fmaxf(mx[r], fabsf(acc[c][r] * SQ));
#pragma unroll
    for (int msk = 1; msk < 16; msk <<= 1)
#pragma unroll
      for (int r = 0; r < 4; ++r) mx[r] = fmaxf(mx[r], __shfl_xor(mx[r], msk));
    float C2[4];
#pragma unroll
    for (int r = 0; r < 4; ++r) C2[r] = __expf(-2.f * mx[r]);
#pragma unroll
    for (int c = 0; c < 16; ++c)
#pragma unroll
      for (int r = 0; r < 4; ++r) {
        const float e1 = __expf(acc[c][r] * SQ - mx[r]);
        sm[r] += e1 + C2[r] * __builtin_amdgcn_rcpf(e1);
        acc[c][r] = e1;
      }
#pragma unroll
    for (int msk = 1; msk < 16; msk <<= 1)
#pragma unroll
      for (int r = 0; r < 4; ++r) sm[r] += __shfl_xor(sm[r], msk);
    float inv[4], K2[4];
#pragma unroll
    for (int r = 0; r < 4; ++r) {
      inv[r] = __builtin_amdgcn_rcpf(sm[r]);
      K2[r] = C2[r] * inv[r];
    }
#pragma unroll
    for (int ch = 0; ch < 4; ++ch) {
      __syncthreads();
      if ((m >> 3) == (ch & 1)) {
        const int colb = (m & 7) * 16;
        const bool neg = (ch >= 2);
#pragma unroll
        for (int r = 0; r < 4; ++r) {
          const int row = wv * 16 + q * 4 + r;
          __bf16 vv[16];
          if (!neg) {
#pragma unroll
            for (int c = 0; c < 16; ++c) vv[c] = (__bf16)(acc[c][r] * inv[r]);
          } else {
#pragma unroll
            for (int c = 0; c < 16; ++c)
              vv[c] = (__bf16)(K2[r] * __builtin_amdgcn_rcpf(acc[c][r]));
          }
          *reinterpret_cast<bf16x8*>(&S.f.Qtmp[row][colb])     = *reinterpret_cast<bf16x8*>(&vv[0]);
          *reinterpret_cast<bf16x8*>(&S.f.Qtmp[row][colb + 8]) = *reinterpret_cast<bf16x8*>(&vv[8]);
        }
      }
      __syncthreads();
#pragma unroll
      for (int kk = 0; kk < 4; ++kk)
        qT[ch * 4 + kk] = *reinterpret_cast<const bf16x8*>(&S.f.Qtmp[wv * 16 + m][kk * 32 + q * 8]);
    }
  }
  __syncthreads();

  // ---------------- main loop (validated rounds 7-9) ----------------
  f32x4 oA[5], oB[5];
#pragma unroll
  for (int i = 0; i < 5; ++i) { oA[i] = f32x4{0.f, 0.f, 0.f, 0.f}; oB[i] = oA[i]; }

  if (tid < 64) S.mn.Vt[64][tid] = (__bf16)1.0f;
  for (int z = tid; z < 15 * 64; z += 256) S.mn.Vt[65 + (z >> 6)][z & 63] = (__bf16)0.f;

  const int vrow = tid >> 2, vc0 = (tid & 3) * 16;
  const int krow = tid >> 2, kc0 = (tid & 3) * 32;
  const __bf16* vbase = vt + ((long)bh * 64 + vrow) * 256 + vc0;
  const __bf16* kbase = kf + ((long)(bh * 256 + krow)) * FD + kc0;
  bf16x8 vr0, vr1, kr[4];
  vr0 = *reinterpret_cast<const bf16x8*>(vbase);
  vr1 = *reinterpret_cast<const bf16x8*>(vbase + 8);
#pragma unroll
  for (int j = 0; j < 4; ++j) kr[j] = *reinterpret_cast<const bf16x8*>(kbase + j * 8);

  for (int st = 0; st <= tB; ++st) {
    const bool aA = (st <= tA);
    f32x4 sA[4], sB[4];
#pragma unroll
    for (int i = 0; i < 4; ++i) { sA[i] = f32x4{0.f, 0.f, 0.f, 0.f}; sB[i] = sA[i]; }
#pragma unroll
    for (int ch = 0; ch < 4; ++ch) {
      __syncthreads();
      if (ch == 0) {
        *reinterpret_cast<bf16x8*>(&S.mn.Vt[vrow][vc0])     = vr0;
        *reinterpret_cast<bf16x8*>(&S.mn.Vt[vrow][vc0 + 8]) = vr1;
      }
#pragma unroll
      for (int j = 0; j < 4; ++j)
        *reinterpret_cast<bf16x8*>(&S.mn.Kc[krow][kc0 + j * 8]) = kr[j];
      if (ch < 3) {
        const __bf16* kp = kbase + (long)st * 64 * FD + (ch + 1) * 128;
#pragma unroll
        for (int j = 0; j < 4; ++j) kr[j] = *reinterpret_cast<const bf16x8*>(kp + j * 8);
      } else if (st < tB) {
        const __bf16* kp = kbase + (long)(st + 1) * 64 * FD;
#pragma unroll
        for (int j = 0; j < 4; ++j) kr[j] = *reinterpret_cast<const bf16x8*>(kp + j * 8);
        vr0 = *reinterpret_cast<const bf16x8*>(vbase + (st + 1) * 64);
        vr1 = *reinterpret_cast<const bf16x8*>(vbase + (st + 1) * 64 + 8);
      }
      __syncthreads();
#pragma unroll
      for (int kk = 0; kk < 4; ++kk) {
#pragma unroll
        for (int c = 0; c < 4; ++c) {
          const bf16x8 bf = *reinterpret_cast<const bf16x8*>(&S.mn.Kc[c * 16 + m][kk * 32 + q * 8]);
          sB[c] = MFMA16(qB[ch * 4 + kk], bf, sB[c]);
          if (aA) sA[c] = MFMA16(qA[ch * 4 + kk], bf, sA[c]);
        }
      }
    }
    {
      const bool mask = (st == tB);
#pragma unroll
      for (int c = 0; c < 4; ++c)
#pragma unroll
        for (int r = 0; r < 4; ++r) {
          const int row = wv * 16 + q * 4 + r, col = c * 16 + m;
          S.mn.Pt[row][col] = (__bf16)((mask && col > row) ? 0.f : sB[c][r]);
        }
#pragma unroll
      for (int kk = 0; kk < 2; ++kk) {
        const bf16x8 pf = *reinterpret_cast<const bf16x8*>(&S.mn.Pt[wv * 16 + m][kk * 32 + q * 8]);
#pragma unroll
        for (int c = 0; c < 5; ++c) {
          const bf16x8 vf = *reinterpret_cast<const bf16x8*>(&S.mn.Vt[c * 16 + m][kk * 32 + q * 8]);
          oB[c] = MFMA16(pf, vf, oB[c]);
        }
      }
    }
    if (aA) {
      const bool mask = (st == tA);
#pragma unroll
      for (int c = 0; c < 4; ++c)
#pragma unroll
        for (int r = 0; r < 4; ++r) {
          const int row = wv * 16 + q * 4 + r, col = c * 16 + m;
          S.mn.Pt[row][col] = (__bf16)((mask && col > row) ? 0.f : sA[c][r]);
        }
#pragma unroll
      for (int kk = 0; kk < 2; ++kk) {
        const bf16x8 pf = *reinterpret_cast<const bf16x8*>(&S.mn.Pt[wv * 16 + m][kk * 32 + q * 8]);
#pragma unroll
        for (int c = 0; c < 5; ++c) {
          const bf16x8 vf = *reinterpret_cast<const bf16x8*>(&S.mn.Vt[c * 16 + m][kk * 32 + q * 8]);
          oA[c] = MFMA16(pf, vf, oA[c]);
        }
      }
    }
  }
#pragma unroll
  for (int r = 0; r < 4; ++r) {
    const float denB = __shfl(oB[4][r], (lane & 48));
    const float invB = 0.125f / (denB + 1e-5f);          // SCALE=64^-0.5, EPS
    const int rowB = tB * 64 + wv * 16 + q * 4 + r;
#pragma unroll
    for (int c = 0; c < 4; ++c)
      att[((long)(rowB * B_SZ + b)) * DM + h * DH + c * 16 + m] = (__bf16)(oB[c][r] * invB);
    const float denA = __shfl(oA[4][r], (lane & 48));
    const float invA = 0.125f / (denA + 1e-5f);
    const int rowA = tA * 64 + wv * 16 + q * 4 + r;
#pragma unroll
    for (int c = 0; c < 4; ++c)
      att[((long)(rowA * B_SZ + b)) * DM + h * DH + c * 16 + m] = (__bf16)(oA[c][r] * invA);
  }
}

// ---------------------------------------------------------------------------
// K4: xrow(bf16) = hb + att @ w_o, 64x128 tile + register prefetch (round 10:
// bf16 intermediate — halves the xrow roundtrip traffic; precision fine at
// 3x error margin).
// ---------------------------------------------------------------------------
__global__ __launch_bounds__(256) void gemm_att_wo(const __bf16* __restrict__ A,
                                                   const __bf16* __restrict__ Bt,
                                                   const __bf16* __restrict__ hb,
                                                   __bf16* __restrict__ xrow) {
  __shared__ __bf16 At[64][136];
  __shared__ __bf16 Bts[128][136];
  const int n0 = blockIdx.x * 128, m0 = blockIdx.y * 64;
  const int tid = threadIdx.x, lane = tid & 63, wv = tid >> 6;
  const int m = lane & 15, q = lane >> 4;
  const int ra = tid >> 2, ca = (tid & 3) * 32;
  const int rb = tid >> 1, cb = (tid & 1) * 64;
  const __bf16* ap = A + (long)(m0 + ra) * DM + ca;
  const __bf16* bp = Bt + (long)(n0 + rb) * DM + cb;
  f32x4 acc[8];
#pragma unroll
  for (int i = 0; i < 8; ++i) acc[i] = f32x4{0.f, 0.f, 0.f, 0.f};

  bf16x8 ar[4], br[8];
#pragma unroll
  for (int j = 0; j < 4; ++j) ar[j] = *reinterpret_cast<const bf16x8*>(ap + j * 8);
#pragma unroll
  for (int j = 0; j < 8; ++j) br[j] = *reinterpret_cast<const bf16x8*>(bp + j * 8);
  for (int k0 = 0; k0 < DM; k0 += 128) {
    __syncthreads();
#pragma unroll
    for (int j = 0; j < 4; ++j) *reinterpret_cast<bf16x8*>(&At[ra][ca + j * 8]) = ar[j];
#pragma unroll
    for (int j = 0; j < 8; ++j) *reinterpret_cast<bf16x8*>(&Bts[rb][cb + j * 8]) = br[j];
    if (k0 + 128 < DM) {
#pragma unroll
      for (int j = 0; j < 4; ++j)
        ar[j] = *reinterpret_cast<const bf16x8*>(ap + k0 + 128 + j * 8);
#pragma unroll
      for (int j = 0; j < 8; ++j)
        br[j] = *reinterpret_cast<const bf16x8*>(bp + k0 + 128 + j * 8);
    }
    __syncthreads();
#pragma unroll
    for (int kk = 0; kk < 4; ++kk) {
      const bf16x8 af = *reinterpret_cast<const bf16x8*>(&At[wv * 16 + m][kk * 32 + q * 8]);
#pragma unroll
      for (int c = 0; c < 8; ++c) {
        const bf16x8 bf = *reinterpret_cast<const bf16x8*>(&Bts[c * 16 + m][kk * 32 + q * 8]);
        acc[c] = MFMA16(af, bf, acc[c]);
      }
    }
  }
#pragma unroll
  for (int r2 = 0; r2 < 4; ++r2)
#pragma unroll
    for (int c = 0; c < 8; ++c) {
      const long row = m0 + wv * 16 + q * 4 + r2;
      const long col = n0 + c * 16 + m;
      xrow[row * DM + col] = (__bf16)(acc[c][r2] + (float)hb[row * DM + col]);
    }
}

// ---------------------------------------------------------------------------
// K5: LayerNorm rows of xrow (bf16) -> out (validated; bf16 input round 10).
// ---------------------------------------------------------------------------
__global__ __launch_bounds__(256) void ln_out(const __bf16* __restrict__ xrow,
                                              const __bf16* __restrict__ gamma,
                                              const __bf16* __restrict__ beta,
                                              const int* __restrict__ flag,
                                              void* __restrict__ out) {
  const int f32 = flag[0];
  const int r = blockIdx.x;
  const int tid = threadIdx.x;
  __shared__ float red[256];
  const float x0 = (float)xrow[(long)r * DM + tid];
  const float x1 = (float)xrow[(long)r * DM + tid + 256];

  red[tid] = x0 + x1; __syncthreads();
  for (int s = 128; s > 0; s >>= 1) { if (tid < s) red[tid] += red[tid + s]; __syncthreads(); }
  const float mu = red[0] * (1.f / 512.f); __syncthreads();
  red[tid] = x0 * x0 + x1 * x1; __syncthreads();
  for (int s = 128; s > 0; s >>= 1) { if (tid < s) red[tid] += red[tid + s]; __syncthreads(); }
  const float var = red[0] * (1.f / 512.f) - mu * mu; __syncthreads();
  const float rstd = rsqrtf(var + 1e-5f);

  stmix(out, (long)r * DM + tid,
        (x0 - mu) * rstd * (float)gamma[tid] + (float)beta[tid], f32);
  stmix(out, (long)r * DM + tid + 256,
        (x1 - mu) * rstd * (float)gamma[tid + 256] + (float)beta[tid + 256], f32);
}

// ---------------------------------------------------------------------------
extern "C" void kernel_launch(void* const* d_in, const int* in_sizes, int n_in,
                              void* d_out, int out_size, void* d_ws, size_t ws_size,
                              hipStream_t stream) {
  (void)in_sizes; (void)n_in; (void)out_size; (void)ws_size;
  char* ws = (char*)d_ws;
  __bf16* qkv   = (__bf16*)ws;
  int*    flag  = (int*)(ws + 33554432);
  __bf16* wt    = (__bf16*)(ws + 33554688);
  __bf16* wot   = (__bf16*)(ws + 35651840);
  __bf16* att   = (__bf16*)(ws + 36176128);
  __bf16* vt    = (__bf16*)(ws + 44564736);
  __bf16* hb    = (__bf16*)(ws + 52953344);
  __bf16* projT = (__bf16*)(ws + 61341952);
  __bf16* pi0b  = (__bf16*)(ws + 61374720);
  __bf16* pi1b  = (__bf16*)(ws + 61378816);
  __bf16* gamb  = (__bf16*)(ws + 61382912);
  __bf16* betb  = (__bf16*)(ws + 61383936);
  __bf16* xrow  = (__bf16*)(ws + 61384960);  // bf16 now
  __bf16* kf    = (__bf16*)(ws + 128493824);

  prep<<<PREP_BLOCKS, 256, 0, stream>>>(d_in[0], d_in[1], d_in[2], d_in[7],
                                        d_in[5], d_in[6], d_in[3], d_in[4],
                                        flag, hb, wt, wot, projT,
                                        pi0b, pi1b, gamb, betb);
  gemm_h_wqkv<<<dim3(QKVN / 128, ROWS / 64), 256, 0, stream>>>(hb, wt, qkv);
  features_mfma<<<dim3(4, 256), 256, 0, stream>>>(qkv, projT, pi0b, pi1b, kf, vt);
  flash_mfma<<<dim3(512), 256, 0, stream>>>(qkv, projT, kf, vt, att);
  gemm_att_wo<<<dim3(DM / 128, ROWS / 64), 256, 0, stream>>>(att, wot, hb, xrow);
  ln_out<<<dim3(ROWS), 256, 0, stream>>>(xrow, gamb, betb, flag, d_out);
}